// Round 9
// baseline (297.192 us; speedup 1.0000x reference)
//
#include <hip/hip_runtime.h>

// Problem constants (fixed by reference)
#define IN_DIM  256
#define HID_DIM 256
#define H2_DIM  128
#define EMB_DIM 64
#define K_CODES 4096
#define EPS_BN  1e-5f

// Journal: R3 __launch_bounds__(256,N) VGPR-clamp -> spill. R4 full unroll ->
// spill; unroll<=2. R5/R6 fp16 hi/lo split GEMMs on MFMA, absmax 0.
// R7/R8 FAILED (identical absmax 1156, deterministic): folding -0.5||e||^2
// into the MFMA C-INIT makes all 12 chained fp32 adds round at |nv|~32 scale
// (error ~1.2e-5) vs R5/R6's late subtract (~2e-6); a fixed near-tie row
// flips. LESSON: keep additive constants OUT of long accumulations; subtract
// once at the end. R9: bit-exact R5/R6 scoring (two chains, late -nv) +
// the two safe structural wins: A-frags direct from global (no LDS
// read-pend/overwrite hazard) and 36.5 KB LDS -> 4 blocks/CU.

typedef _Float16 f16;
typedef _Float16 f16x4 __attribute__((ext_vector_type(4)));
typedef _Float16 f16x8 __attribute__((ext_vector_type(8)));
typedef float    f32x16 __attribute__((ext_vector_type(16)));

// ---------------------------------------------------------------------------
// Kernel 0a: half squared norms of codebook rows: norms[c] = 0.5*||e_c||^2
// ---------------------------------------------------------------------------
__global__ __launch_bounds__(256) void k_norms(const float* __restrict__ cb,
                                               float* __restrict__ norms) {
    int c = blockIdx.x * 256 + threadIdx.x;
    const float4* row = reinterpret_cast<const float4*>(cb + (size_t)c * EMB_DIM);
    float s = 0.f;
#pragma unroll
    for (int i = 0; i < EMB_DIM / 4; ++i) {
        float4 v = row[i];
        s += v.x * v.x + v.y * v.y + v.z * v.z + v.w * v.w;
    }
    norms[c] = 0.5f * s;
}

// ---------------------------------------------------------------------------
// Kernel 0b: split W1/W2/W3/codebook into fp16 hi/lo planes.
// Unified index: [0,65536) W1 | [.,98304) W2 | [.,106496) W3 | [.,368640) cb
// ---------------------------------------------------------------------------
__global__ __launch_bounds__(256) void k_prep(
    const float* __restrict__ W1, const float* __restrict__ W2,
    const float* __restrict__ W3, const float* __restrict__ cb,
    f16* __restrict__ w1h, f16* __restrict__ w1l,
    f16* __restrict__ w2h, f16* __restrict__ w2l,
    f16* __restrict__ w3h, f16* __restrict__ w3l,
    f16* __restrict__ cbh, f16* __restrict__ cbl) {
    int i = blockIdx.x * 256 + threadIdx.x;   // < 368640
    const float* src; f16 *dh, *dl; int off;
    if (i < 65536)       { src = W1; dh = w1h; dl = w1l; off = i; }
    else if (i < 98304)  { src = W2; dh = w2h; dl = w2l; off = i - 65536; }
    else if (i < 106496) { src = W3; dh = w3h; dl = w3l; off = i - 98304; }
    else                 { src = cb; dh = cbh; dl = cbl; off = i - 106496; }
    float v = src[off];
    f16 h = (f16)v;
    dh[off] = h;
    dl[off] = (f16)(v - (float)h);
}

// ---------------------------------------------------------------------------
// Kernel 1: fused MFMA encoder (unchanged from R6 — proven).
// ---------------------------------------------------------------------------
__global__ __launch_bounds__(256) void k_encoder_mfma(
    const float* __restrict__ x,
    const f16* __restrict__ w1h, const f16* __restrict__ w1l,
    const f16* __restrict__ w2h, const f16* __restrict__ w2l,
    const f16* __restrict__ w3h, const f16* __restrict__ w3l,
    const float* __restrict__ b1,
    const float* __restrict__ gm, const float* __restrict__ bt,
    const float* __restrict__ mu, const float* __restrict__ vr,
    const float* __restrict__ b2, const float* __restrict__ b3,
    f16* __restrict__ Zh, f16* __restrict__ Zl) {
    __shared__ __align__(16) f16 sm[27136];  // 53.0 KB
    const int tid  = threadIdx.x;
    const int lane = tid & 63;
    const int w    = tid >> 6;
    const int ln31 = lane & 31;
    const int q    = lane >> 5;
    const int r0   = blockIdx.x * 32;

    // ================= Stage 1: h1 = BN+ReLU(x @ W1^T) ======================
    f32x16 acc1a = {};
    f32x16 acc1b = {};
#pragma unroll 1
    for (int kc = 0; kc < 8; ++kc) {
        __syncthreads();
        {
            int row = tid >> 3, c = (tid & 7) * 4;
            float4 v = *reinterpret_cast<const float4*>(
                x + (size_t)(r0 + row) * IN_DIM + kc * 32 + c);
            f16x4 hv, lv;
            hv[0] = (f16)v.x; lv[0] = (f16)(v.x - (float)hv[0]);
            hv[1] = (f16)v.y; lv[1] = (f16)(v.y - (float)hv[1]);
            hv[2] = (f16)v.z; lv[2] = (f16)(v.z - (float)hv[2]);
            hv[3] = (f16)v.w; lv[3] = (f16)(v.w - (float)hv[3]);
            *(f16x4*)(sm + row * 40 + c)        = hv;
            *(f16x4*)(sm + 1280 + row * 40 + c) = lv;
        }
#pragma unroll
        for (int it = 0; it < 4; ++it) {
            int i = it * 256 + tid;
            int j = i >> 2, c8 = (i & 3) * 8;
            *(f16x8*)(sm + 2560 + j * 40 + c8) =
                *(const f16x8*)(w1h + j * IN_DIM + kc * 32 + c8);
            *(f16x8*)(sm + 12800 + j * 40 + c8) =
                *(const f16x8*)(w1l + j * IN_DIM + kc * 32 + c8);
        }
        __syncthreads();
#pragma unroll
        for (int ks = 0; ks < 2; ++ks) {
            f16x8 ah = *(const f16x8*)(sm + ln31 * 40 + ks * 16 + q * 8);
            f16x8 al = *(const f16x8*)(sm + 1280 + ln31 * 40 + ks * 16 + q * 8);
            int j0 = (w * 64 + ln31) * 40 + ks * 16 + q * 8;
            f16x8 bh0 = *(const f16x8*)(sm + 2560 + j0);
            f16x8 bl0 = *(const f16x8*)(sm + 12800 + j0);
            f16x8 bh1 = *(const f16x8*)(sm + 2560 + j0 + 32 * 40);
            f16x8 bl1 = *(const f16x8*)(sm + 12800 + j0 + 32 * 40);
            acc1a = __builtin_amdgcn_mfma_f32_32x32x16_f16(ah, bh0, acc1a, 0, 0, 0);
            acc1b = __builtin_amdgcn_mfma_f32_32x32x16_f16(ah, bh1, acc1b, 0, 0, 0);
            acc1a = __builtin_amdgcn_mfma_f32_32x32x16_f16(al, bh0, acc1a, 0, 0, 0);
            acc1b = __builtin_amdgcn_mfma_f32_32x32x16_f16(al, bh1, acc1b, 0, 0, 0);
            acc1a = __builtin_amdgcn_mfma_f32_32x32x16_f16(ah, bl0, acc1a, 0, 0, 0);
            acc1b = __builtin_amdgcn_mfma_f32_32x32x16_f16(ah, bl1, acc1b, 0, 0, 0);
        }
    }
    __syncthreads();

    // BN + ReLU epilogue; write h1 hi/lo planes (stride 264).
    {
#pragma unroll
        for (int nt = 0; nt < 2; ++nt) {
            int j = w * 64 + nt * 32 + ln31;
            float sc = gm[j] * rsqrtf(vr[j] + EPS_BN);
            float sh = (b1[j] - mu[j]) * sc + bt[j];
            const f32x16& a = nt ? acc1b : acc1a;
#pragma unroll
            for (int r = 0; r < 16; ++r) {
                int row = (r & 3) + 8 * (r >> 2) + 4 * q;
                float v = a[r] * sc + sh;
                v = v > 0.f ? v : 0.f;
                f16 h = (f16)v;
                sm[row * 264 + j]        = h;
                sm[8448 + row * 264 + j] = (f16)(v - (float)h);
            }
        }
    }

    // ================= Stage 2: h2 = ReLU(h1 @ W2^T + b2) ===================
    f32x16 acc2a = {};
    f32x16 acc2b = {};
#pragma unroll 1
    for (int kc = 0; kc < 8; ++kc) {
        __syncthreads();
#pragma unroll
        for (int it = 0; it < 2; ++it) {
            int i = it * 256 + tid;
            int j = i >> 2, c8 = (i & 3) * 8;
            *(f16x8*)(sm + 16896 + j * 40 + c8) =
                *(const f16x8*)(w2h + j * HID_DIM + kc * 32 + c8);
            *(f16x8*)(sm + 22016 + j * 40 + c8) =
                *(const f16x8*)(w2l + j * HID_DIM + kc * 32 + c8);
        }
        __syncthreads();
#pragma unroll
        for (int ks = 0; ks < 2; ++ks) {
            f16x8 ah = *(const f16x8*)(sm + ln31 * 264 + kc * 32 + ks * 16 + q * 8);
            f16x8 al = *(const f16x8*)(sm + 8448 + ln31 * 264 + kc * 32 + ks * 16 + q * 8);
            int j0 = (w * 32 + ln31) * 40 + ks * 16 + q * 8;
            f16x8 bh = *(const f16x8*)(sm + 16896 + j0);
            f16x8 bl = *(const f16x8*)(sm + 22016 + j0);
            f32x16& acc = ks ? acc2b : acc2a;
            acc = __builtin_amdgcn_mfma_f32_32x32x16_f16(ah, bh, acc, 0, 0, 0);
            acc = __builtin_amdgcn_mfma_f32_32x32x16_f16(al, bh, acc, 0, 0, 0);
            acc = __builtin_amdgcn_mfma_f32_32x32x16_f16(ah, bl, acc, 0, 0, 0);
        }
    }
    __syncthreads();

    // ReLU epilogue -> h2 planes (stride 136); stage W3 [64 j3][128 k] hi/lo.
    {
        int j2 = w * 32 + ln31;
        float bias = b2[j2];
#pragma unroll
        for (int r = 0; r < 16; ++r) {
            int row = (r & 3) + 8 * (r >> 2) + 4 * q;
            float v = (acc2a[r] + acc2b[r]) + bias;
            v = v > 0.f ? v : 0.f;
            f16 h = (f16)v;
            sm[row * 136 + j2]        = h;
            sm[4352 + row * 136 + j2] = (f16)(v - (float)h);
        }
#pragma unroll
        for (int it = 0; it < 4; ++it) {
            int i = it * 256 + tid;
            int j = i >> 4, c8 = (i & 15) * 8;
            *(f16x8*)(sm + 8704 + j * 136 + c8) =
                *(const f16x8*)(w3h + j * H2_DIM + c8);
            *(f16x8*)(sm + 17408 + j * 136 + c8) =
                *(const f16x8*)(w3l + j * H2_DIM + c8);
        }
    }
    __syncthreads();

    // ================= Stage 3: z = tanh(h2 @ W3^T + b3) ====================
    if (w < 2) {
        f32x16 acc3a = {};
        f32x16 acc3b = {};
#pragma unroll 2
        for (int ks = 0; ks < 8; ++ks) {
            f16x8 ah = *(const f16x8*)(sm + ln31 * 136 + ks * 16 + q * 8);
            f16x8 al = *(const f16x8*)(sm + 4352 + ln31 * 136 + ks * 16 + q * 8);
            int j0 = 8704 + (w * 32 + ln31) * 136 + ks * 16 + q * 8;
            f16x8 bh = *(const f16x8*)(sm + j0);
            f16x8 bl = *(const f16x8*)(sm + j0 + 8704);
            f32x16& acc = (ks & 1) ? acc3b : acc3a;
            acc = __builtin_amdgcn_mfma_f32_32x32x16_f16(ah, bh, acc, 0, 0, 0);
            acc = __builtin_amdgcn_mfma_f32_32x32x16_f16(al, bh, acc, 0, 0, 0);
            acc = __builtin_amdgcn_mfma_f32_32x32x16_f16(ah, bl, acc, 0, 0, 0);
        }
        int j3 = w * 32 + ln31;
        float bias = b3[j3];
#pragma unroll
        for (int r = 0; r < 16; ++r) {
            int row = (r & 3) + 8 * (r >> 2) + 4 * q;
            float zv = tanhf((acc3a[r] + acc3b[r]) + bias);
            f16 h = (f16)zv;
            size_t idx = (size_t)(r0 + row) * EMB_DIM + j3;
            Zh[idx] = h;
            Zl[idx] = (f16)(zv - (float)h);
        }
    }
}

// ---------------------------------------------------------------------------
// Kernel 2: MFMA argmin, R9. 128 rows/block, 128-code chunks.
// Scoring arithmetic BIT-IDENTICAL to R5/R6 (two chains init 0, hh/lh/hl
// pair-interleaved, t = (acc0+acc1) - nv late subtract). A-frags direct from
// global; LDS = eb tiles + norms only: 36.5 KB -> 4 blocks/CU.
// ---------------------------------------------------------------------------
__global__ __launch_bounds__(256) void k_argmin_mfma(
    const f16* __restrict__ Zh, const f16* __restrict__ Zl,
    const f16* __restrict__ cbh, const f16* __restrict__ cbl,
    const float* __restrict__ norms, int* __restrict__ out) {
    __shared__ __align__(16) f16 sm[18688];  // 36.5 KB -> 4 blocks/CU
    f16* ebh = sm;            // [128][72]
    f16* ebl = sm + 9216;     // [128][72]
    float* nbuf = (float*)(sm + 18432);  // [128]
    const int tid  = threadIdx.x;
    const int lane = tid & 63;
    const int w    = tid >> 6;
    const int ln31 = lane & 31;
    const int q    = lane >> 5;
    const int r0   = blockIdx.x * 128;

    // A fragments straight from global (16 B aligned, read once, L2-served).
    f16x8 ah[4], al[4];
    {
        const f16* zrh = Zh + (size_t)(r0 + w * 32 + ln31) * EMB_DIM;
        const f16* zrl = Zl + (size_t)(r0 + w * 32 + ln31) * EMB_DIM;
#pragma unroll
        for (int ks = 0; ks < 4; ++ks) {
            ah[ks] = *(const f16x8*)(zrh + ks * 16 + q * 8);
            al[ks] = *(const f16x8*)(zrl + ks * 16 + q * 8);
        }
    }

    float bv[16];
    int   bi[16];
#pragma unroll
    for (int i = 0; i < 16; ++i) { bv[i] = -3.4e38f; bi[i] = 0; }

    for (int ch = 0; ch < K_CODES / 128; ++ch) {
        __syncthreads();  // prior chunk's B-frag reads done (used pre-barrier)
        const float4* srch = (const float4*)(cbh + (size_t)ch * 128 * EMB_DIM);
        const float4* srcl = (const float4*)(cbl + (size_t)ch * 128 * EMB_DIM);
        float4* dsth = (float4*)ebh;
        float4* dstl = (float4*)ebl;
#pragma unroll
        for (int it = 0; it < 4; ++it) {
            int i = it * 256 + tid;
            int row = i >> 3, c8 = i & 7;
            dsth[row * 9 + c8] = srch[row * 8 + c8];
            dstl[row * 9 + c8] = srcl[row * 8 + c8];
        }
        if (tid < 128) nbuf[tid] = norms[ch * 128 + tid];
        __syncthreads();

#pragma unroll 1
        for (int ct = 0; ct < 4; ++ct) {
            f16x8 bh[4], bl[4];
#pragma unroll
            for (int ks = 0; ks < 4; ++ks) {
                int off = (ct * 32 + ln31) * 72 + ks * 16 + q * 8;
                bh[ks] = *(const f16x8*)(ebh + off);
                bl[ks] = *(const f16x8*)(ebl + off);
            }
            f32x16 acc0 = {};
            f32x16 acc1 = {};
#pragma unroll
            for (int ks = 0; ks < 4; ks += 2) {  // R5/R6 exact order
                acc0 = __builtin_amdgcn_mfma_f32_32x32x16_f16(ah[ks],     bh[ks],     acc0, 0, 0, 0);
                acc1 = __builtin_amdgcn_mfma_f32_32x32x16_f16(ah[ks + 1], bh[ks + 1], acc1, 0, 0, 0);
                acc0 = __builtin_amdgcn_mfma_f32_32x32x16_f16(al[ks],     bh[ks],     acc0, 0, 0, 0);
                acc1 = __builtin_amdgcn_mfma_f32_32x32x16_f16(al[ks + 1], bh[ks + 1], acc1, 0, 0, 0);
                acc0 = __builtin_amdgcn_mfma_f32_32x32x16_f16(ah[ks],     bl[ks],     acc0, 0, 0, 0);
                acc1 = __builtin_amdgcn_mfma_f32_32x32x16_f16(ah[ks + 1], bl[ks + 1], acc1, 0, 0, 0);
            }
            float nv  = nbuf[ct * 32 + ln31];
            int   col = ch * 128 + ct * 32 + ln31;
#pragma unroll
            for (int r = 0; r < 16; ++r) {
                float t  = (acc0[r] + acc1[r]) - nv;
                bool  gt = t > bv[r];
                bv[r] = gt ? t : bv[r];
                bi[r] = gt ? col : bi[r];
            }
        }
    }

    // Reduce across the 32 lanes (ln31) sharing each row; stride 33 words.
    __syncthreads();
    float* redv = (float*)sm;            // [128][33] floats (16.9 KB)
    int*   redi = (int*)(sm + 8448);     // [128][33] ints  (16.9 KB)
#pragma unroll
    for (int r = 0; r < 16; ++r) {
        int row = (r & 3) + 8 * (r >> 2) + 4 * q + 32 * w;
        redv[row * 33 + ln31] = bv[r];
        redi[row * 33 + ln31] = bi[r];
    }
    __syncthreads();
    if (tid < 128) {
        float v  = redv[tid * 33];
        int   ix = redi[tid * 33];
#pragma unroll
        for (int j = 1; j < 32; ++j) {
            float vj = redv[tid * 33 + j];
            int   ij = redi[tid * 33 + j];
            if (vj > v) { v = vj; ix = ij; }
        }
        out[r0 + tid] = ix;
    }
}

// ---------------------------------------------------------------------------
extern "C" void kernel_launch(void* const* d_in, const int* in_sizes, int n_in,
                              void* d_out, int out_size, void* d_ws, size_t ws_size,
                              hipStream_t stream) {
    (void)n_in; (void)out_size; (void)ws_size;
    const float* x  = (const float*)d_in[0];
    const float* W1 = (const float*)d_in[1];
    const float* b1 = (const float*)d_in[2];
    const float* gm = (const float*)d_in[3];
    const float* bt = (const float*)d_in[4];
    const float* mu = (const float*)d_in[5];
    const float* vr = (const float*)d_in[6];
    const float* W2 = (const float*)d_in[7];
    const float* b2 = (const float*)d_in[8];
    const float* W3 = (const float*)d_in[9];
    const float* b3 = (const float*)d_in[10];
    const float* cb = (const float*)d_in[11];

    // Workspace layout (~17.4 MB)
    char* ws = (char*)d_ws;
    float* norms = (float*)ws;                    // 16 KB
    f16* cbh = (f16*)(ws + 16384);                // 512 KB
    f16* cbl = (f16*)(ws + 540672);               // 512 KB
    f16* w1h = (f16*)(ws + 1064960);              // 128 KB
    f16* w1l = (f16*)(ws + 1196032);              // 128 KB
    f16* w2h = (f16*)(ws + 1327104);              // 64 KB
    f16* w2l = (f16*)(ws + 1392640);              // 64 KB
    f16* w3h = (f16*)(ws + 1458176);              // 16 KB
    f16* w3l = (f16*)(ws + 1474560);              // 16 KB
    f16* Zh  = (f16*)(ws + 1490944);              // 8 MB
    f16* Zl  = (f16*)(ws + 9879552);              // 8 MB
    int* out = (int*)d_out;

    const int B = in_sizes[0] / IN_DIM;  // 65536

    k_norms<<<K_CODES / 256, 256, 0, stream>>>(cb, norms);
    k_prep<<<1440, 256, 0, stream>>>(W1, W2, W3, cb, w1h, w1l, w2h, w2l,
                                     w3h, w3l, cbh, cbl);
    k_encoder_mfma<<<B / 32, 256, 0, stream>>>(x, w1h, w1l, w2h, w2l, w3h, w3l,
                                               b1, gm, bt, mu, vr, b2, b3, Zh, Zl);
    k_argmin_mfma<<<B / 128, 256, 0, stream>>>(Zh, Zl, cbh, cbl, norms, out);
}

// Round 10
// 296.757 us; speedup vs baseline: 1.0015x; 1.0015x over previous
//
#include <hip/hip_runtime.h>

// Problem constants (fixed by reference)
#define IN_DIM  256
#define HID_DIM 256
#define H2_DIM  128
#define EMB_DIM 64
#define K_CODES 4096
#define EPS_BN  1e-5f

// Journal: R3 launch_bounds(256,N) VGPR-clamp -> spill. R4 full unroll ->
// spill; unroll<=2. R5/R6 fp16 hi/lo split GEMMs on MFMA, absmax 0.
// R7/R8 FAILED deterministically: -0.5||e||^2 in the MFMA C-init makes all
// 12 chained adds round at |nv|~32 (err ~1.2e-5 vs 2e-6) -> near-tie row
// flips. Keep constants out of long accumulations. R9: R5 arithmetic + A-frags
// from global: pass, but argmin occupancy pinned at 21% — grid 512 blocks =
// 2 blocks/CU (launch-capacity-limited; VGPR 76 allows 4). R10: split the
// code scan 4-way across blocks (grid 512x4 = 4 blocks/CU) + ordered merge —
// per-score arithmetic and tie-break order bit-identical.

typedef _Float16 f16;
typedef _Float16 f16x4 __attribute__((ext_vector_type(4)));
typedef _Float16 f16x8 __attribute__((ext_vector_type(8)));
typedef float    f32x16 __attribute__((ext_vector_type(16)));

// ---------------------------------------------------------------------------
// Kernel 0a: half squared norms of codebook rows: norms[c] = 0.5*||e_c||^2
// ---------------------------------------------------------------------------
__global__ __launch_bounds__(256) void k_norms(const float* __restrict__ cb,
                                               float* __restrict__ norms) {
    int c = blockIdx.x * 256 + threadIdx.x;
    const float4* row = reinterpret_cast<const float4*>(cb + (size_t)c * EMB_DIM);
    float s = 0.f;
#pragma unroll
    for (int i = 0; i < EMB_DIM / 4; ++i) {
        float4 v = row[i];
        s += v.x * v.x + v.y * v.y + v.z * v.z + v.w * v.w;
    }
    norms[c] = 0.5f * s;
}

// ---------------------------------------------------------------------------
// Kernel 0b: split W1/W2/W3/codebook into fp16 hi/lo planes.
// ---------------------------------------------------------------------------
__global__ __launch_bounds__(256) void k_prep(
    const float* __restrict__ W1, const float* __restrict__ W2,
    const float* __restrict__ W3, const float* __restrict__ cb,
    f16* __restrict__ w1h, f16* __restrict__ w1l,
    f16* __restrict__ w2h, f16* __restrict__ w2l,
    f16* __restrict__ w3h, f16* __restrict__ w3l,
    f16* __restrict__ cbh, f16* __restrict__ cbl) {
    int i = blockIdx.x * 256 + threadIdx.x;   // < 368640
    const float* src; f16 *dh, *dl; int off;
    if (i < 65536)       { src = W1; dh = w1h; dl = w1l; off = i; }
    else if (i < 98304)  { src = W2; dh = w2h; dl = w2l; off = i - 65536; }
    else if (i < 106496) { src = W3; dh = w3h; dl = w3l; off = i - 98304; }
    else                 { src = cb; dh = cbh; dl = cbl; off = i - 106496; }
    float v = src[off];
    f16 h = (f16)v;
    dh[off] = h;
    dl[off] = (f16)(v - (float)h);
}

// ---------------------------------------------------------------------------
// Kernel 1: fused MFMA encoder (unchanged from R6 — proven).
// ---------------------------------------------------------------------------
__global__ __launch_bounds__(256) void k_encoder_mfma(
    const float* __restrict__ x,
    const f16* __restrict__ w1h, const f16* __restrict__ w1l,
    const f16* __restrict__ w2h, const f16* __restrict__ w2l,
    const f16* __restrict__ w3h, const f16* __restrict__ w3l,
    const float* __restrict__ b1,
    const float* __restrict__ gm, const float* __restrict__ bt,
    const float* __restrict__ mu, const float* __restrict__ vr,
    const float* __restrict__ b2, const float* __restrict__ b3,
    f16* __restrict__ Zh, f16* __restrict__ Zl) {
    __shared__ __align__(16) f16 sm[27136];  // 53.0 KB
    const int tid  = threadIdx.x;
    const int lane = tid & 63;
    const int w    = tid >> 6;
    const int ln31 = lane & 31;
    const int q    = lane >> 5;
    const int r0   = blockIdx.x * 32;

    // ================= Stage 1: h1 = BN+ReLU(x @ W1^T) ======================
    f32x16 acc1a = {};
    f32x16 acc1b = {};
#pragma unroll 1
    for (int kc = 0; kc < 8; ++kc) {
        __syncthreads();
        {
            int row = tid >> 3, c = (tid & 7) * 4;
            float4 v = *reinterpret_cast<const float4*>(
                x + (size_t)(r0 + row) * IN_DIM + kc * 32 + c);
            f16x4 hv, lv;
            hv[0] = (f16)v.x; lv[0] = (f16)(v.x - (float)hv[0]);
            hv[1] = (f16)v.y; lv[1] = (f16)(v.y - (float)hv[1]);
            hv[2] = (f16)v.z; lv[2] = (f16)(v.z - (float)hv[2]);
            hv[3] = (f16)v.w; lv[3] = (f16)(v.w - (float)hv[3]);
            *(f16x4*)(sm + row * 40 + c)        = hv;
            *(f16x4*)(sm + 1280 + row * 40 + c) = lv;
        }
#pragma unroll
        for (int it = 0; it < 4; ++it) {
            int i = it * 256 + tid;
            int j = i >> 2, c8 = (i & 3) * 8;
            *(f16x8*)(sm + 2560 + j * 40 + c8) =
                *(const f16x8*)(w1h + j * IN_DIM + kc * 32 + c8);
            *(f16x8*)(sm + 12800 + j * 40 + c8) =
                *(const f16x8*)(w1l + j * IN_DIM + kc * 32 + c8);
        }
        __syncthreads();
#pragma unroll
        for (int ks = 0; ks < 2; ++ks) {
            f16x8 ah = *(const f16x8*)(sm + ln31 * 40 + ks * 16 + q * 8);
            f16x8 al = *(const f16x8*)(sm + 1280 + ln31 * 40 + ks * 16 + q * 8);
            int j0 = (w * 64 + ln31) * 40 + ks * 16 + q * 8;
            f16x8 bh0 = *(const f16x8*)(sm + 2560 + j0);
            f16x8 bl0 = *(const f16x8*)(sm + 12800 + j0);
            f16x8 bh1 = *(const f16x8*)(sm + 2560 + j0 + 32 * 40);
            f16x8 bl1 = *(const f16x8*)(sm + 12800 + j0 + 32 * 40);
            acc1a = __builtin_amdgcn_mfma_f32_32x32x16_f16(ah, bh0, acc1a, 0, 0, 0);
            acc1b = __builtin_amdgcn_mfma_f32_32x32x16_f16(ah, bh1, acc1b, 0, 0, 0);
            acc1a = __builtin_amdgcn_mfma_f32_32x32x16_f16(al, bh0, acc1a, 0, 0, 0);
            acc1b = __builtin_amdgcn_mfma_f32_32x32x16_f16(al, bh1, acc1b, 0, 0, 0);
            acc1a = __builtin_amdgcn_mfma_f32_32x32x16_f16(ah, bl0, acc1a, 0, 0, 0);
            acc1b = __builtin_amdgcn_mfma_f32_32x32x16_f16(ah, bl1, acc1b, 0, 0, 0);
        }
    }
    __syncthreads();

    // BN + ReLU epilogue; write h1 hi/lo planes (stride 264).
    {
#pragma unroll
        for (int nt = 0; nt < 2; ++nt) {
            int j = w * 64 + nt * 32 + ln31;
            float sc = gm[j] * rsqrtf(vr[j] + EPS_BN);
            float sh = (b1[j] - mu[j]) * sc + bt[j];
            const f32x16& a = nt ? acc1b : acc1a;
#pragma unroll
            for (int r = 0; r < 16; ++r) {
                int row = (r & 3) + 8 * (r >> 2) + 4 * q;
                float v = a[r] * sc + sh;
                v = v > 0.f ? v : 0.f;
                f16 h = (f16)v;
                sm[row * 264 + j]        = h;
                sm[8448 + row * 264 + j] = (f16)(v - (float)h);
            }
        }
    }

    // ================= Stage 2: h2 = ReLU(h1 @ W2^T + b2) ===================
    f32x16 acc2a = {};
    f32x16 acc2b = {};
#pragma unroll 1
    for (int kc = 0; kc < 8; ++kc) {
        __syncthreads();
#pragma unroll
        for (int it = 0; it < 2; ++it) {
            int i = it * 256 + tid;
            int j = i >> 2, c8 = (i & 3) * 8;
            *(f16x8*)(sm + 16896 + j * 40 + c8) =
                *(const f16x8*)(w2h + j * HID_DIM + kc * 32 + c8);
            *(f16x8*)(sm + 22016 + j * 40 + c8) =
                *(const f16x8*)(w2l + j * HID_DIM + kc * 32 + c8);
        }
        __syncthreads();
#pragma unroll
        for (int ks = 0; ks < 2; ++ks) {
            f16x8 ah = *(const f16x8*)(sm + ln31 * 264 + kc * 32 + ks * 16 + q * 8);
            f16x8 al = *(const f16x8*)(sm + 8448 + ln31 * 264 + kc * 32 + ks * 16 + q * 8);
            int j0 = (w * 32 + ln31) * 40 + ks * 16 + q * 8;
            f16x8 bh = *(const f16x8*)(sm + 16896 + j0);
            f16x8 bl = *(const f16x8*)(sm + 22016 + j0);
            f32x16& acc = ks ? acc2b : acc2a;
            acc = __builtin_amdgcn_mfma_f32_32x32x16_f16(ah, bh, acc, 0, 0, 0);
            acc = __builtin_amdgcn_mfma_f32_32x32x16_f16(al, bh, acc, 0, 0, 0);
            acc = __builtin_amdgcn_mfma_f32_32x32x16_f16(ah, bl, acc, 0, 0, 0);
        }
    }
    __syncthreads();

    // ReLU epilogue -> h2 planes (stride 136); stage W3 [64 j3][128 k] hi/lo.
    {
        int j2 = w * 32 + ln31;
        float bias = b2[j2];
#pragma unroll
        for (int r = 0; r < 16; ++r) {
            int row = (r & 3) + 8 * (r >> 2) + 4 * q;
            float v = (acc2a[r] + acc2b[r]) + bias;
            v = v > 0.f ? v : 0.f;
            f16 h = (f16)v;
            sm[row * 136 + j2]        = h;
            sm[4352 + row * 136 + j2] = (f16)(v - (float)h);
        }
#pragma unroll
        for (int it = 0; it < 4; ++it) {
            int i = it * 256 + tid;
            int j = i >> 4, c8 = (i & 15) * 8;
            *(f16x8*)(sm + 8704 + j * 136 + c8) =
                *(const f16x8*)(w3h + j * H2_DIM + c8);
            *(f16x8*)(sm + 17408 + j * 136 + c8) =
                *(const f16x8*)(w3l + j * H2_DIM + c8);
        }
    }
    __syncthreads();

    // ================= Stage 3: z = tanh(h2 @ W3^T + b3) ====================
    if (w < 2) {
        f32x16 acc3a = {};
        f32x16 acc3b = {};
#pragma unroll 2
        for (int ks = 0; ks < 8; ++ks) {
            f16x8 ah = *(const f16x8*)(sm + ln31 * 136 + ks * 16 + q * 8);
            f16x8 al = *(const f16x8*)(sm + 4352 + ln31 * 136 + ks * 16 + q * 8);
            int j0 = 8704 + (w * 32 + ln31) * 136 + ks * 16 + q * 8;
            f16x8 bh = *(const f16x8*)(sm + j0);
            f16x8 bl = *(const f16x8*)(sm + j0 + 8704);
            f32x16& acc = (ks & 1) ? acc3b : acc3a;
            acc = __builtin_amdgcn_mfma_f32_32x32x16_f16(ah, bh, acc, 0, 0, 0);
            acc = __builtin_amdgcn_mfma_f32_32x32x16_f16(al, bh, acc, 0, 0, 0);
            acc = __builtin_amdgcn_mfma_f32_32x32x16_f16(ah, bl, acc, 0, 0, 0);
        }
        int j3 = w * 32 + ln31;
        float bias = b3[j3];
#pragma unroll
        for (int r = 0; r < 16; ++r) {
            int row = (r & 3) + 8 * (r >> 2) + 4 * q;
            float zv = tanhf((acc3a[r] + acc3b[r]) + bias);
            f16 h = (f16)zv;
            size_t idx = (size_t)(r0 + row) * EMB_DIM + j3;
            Zh[idx] = h;
            Zl[idx] = (f16)(zv - (float)h);
        }
    }
}

// ---------------------------------------------------------------------------
// Kernel 2: MFMA argmin, R10. Grid (B/128, 4): blockIdx.y = code slice.
// Each block scans chunks [slice*8, slice*8+8) (1024 codes) for its 128 rows
// and writes per-row (best, idx) partials. Per-score arithmetic bit-identical
// to R9 (two chains init 0, late -nv). Within-slice order preserved; merge
// (k_merge) folds slices in order -> winner identical to sequential scan.
// ---------------------------------------------------------------------------
__global__ __launch_bounds__(256) void k_argmin_mfma(
    const f16* __restrict__ Zh, const f16* __restrict__ Zl,
    const f16* __restrict__ cbh, const f16* __restrict__ cbl,
    const float* __restrict__ norms,
    float* __restrict__ part_v, int* __restrict__ part_i) {
    __shared__ __align__(16) f16 sm[18688];  // 36.5 KB -> 4 blocks/CU
    f16* ebh = sm;            // [128][72]
    f16* ebl = sm + 9216;     // [128][72]
    float* nbuf = (float*)(sm + 18432);  // [128]
    const int tid   = threadIdx.x;
    const int lane  = tid & 63;
    const int w     = tid >> 6;
    const int ln31  = lane & 31;
    const int q     = lane >> 5;
    const int r0    = blockIdx.x * 128;
    const int slice = blockIdx.y;            // 0..3

    // A fragments straight from global (16 B aligned, read once, L2-served).
    f16x8 ah[4], al[4];
    {
        const f16* zrh = Zh + (size_t)(r0 + w * 32 + ln31) * EMB_DIM;
        const f16* zrl = Zl + (size_t)(r0 + w * 32 + ln31) * EMB_DIM;
#pragma unroll
        for (int ks = 0; ks < 4; ++ks) {
            ah[ks] = *(const f16x8*)(zrh + ks * 16 + q * 8);
            al[ks] = *(const f16x8*)(zrl + ks * 16 + q * 8);
        }
    }

    float bv[16];
    int   bi[16];
#pragma unroll
    for (int i = 0; i < 16; ++i) { bv[i] = -3.4e38f; bi[i] = 0; }

    for (int ch = slice * 8; ch < slice * 8 + 8; ++ch) {
        __syncthreads();  // prior chunk's B-frag reads done (used pre-barrier)
        const float4* srch = (const float4*)(cbh + (size_t)ch * 128 * EMB_DIM);
        const float4* srcl = (const float4*)(cbl + (size_t)ch * 128 * EMB_DIM);
        float4* dsth = (float4*)ebh;
        float4* dstl = (float4*)ebl;
#pragma unroll
        for (int it = 0; it < 4; ++it) {
            int i = it * 256 + tid;
            int row = i >> 3, c8 = i & 7;
            dsth[row * 9 + c8] = srch[row * 8 + c8];
            dstl[row * 9 + c8] = srcl[row * 8 + c8];
        }
        if (tid < 128) nbuf[tid] = norms[ch * 128 + tid];
        __syncthreads();

#pragma unroll 1
        for (int ct = 0; ct < 4; ++ct) {
            f16x8 bh[4], bl[4];
#pragma unroll
            for (int ks = 0; ks < 4; ++ks) {
                int off = (ct * 32 + ln31) * 72 + ks * 16 + q * 8;
                bh[ks] = *(const f16x8*)(ebh + off);
                bl[ks] = *(const f16x8*)(ebl + off);
            }
            f32x16 acc0 = {};
            f32x16 acc1 = {};
#pragma unroll
            for (int ks = 0; ks < 4; ks += 2) {  // R5/R6 exact order
                acc0 = __builtin_amdgcn_mfma_f32_32x32x16_f16(ah[ks],     bh[ks],     acc0, 0, 0, 0);
                acc1 = __builtin_amdgcn_mfma_f32_32x32x16_f16(ah[ks + 1], bh[ks + 1], acc1, 0, 0, 0);
                acc0 = __builtin_amdgcn_mfma_f32_32x32x16_f16(al[ks],     bh[ks],     acc0, 0, 0, 0);
                acc1 = __builtin_amdgcn_mfma_f32_32x32x16_f16(al[ks + 1], bh[ks + 1], acc1, 0, 0, 0);
                acc0 = __builtin_amdgcn_mfma_f32_32x32x16_f16(ah[ks],     bl[ks],     acc0, 0, 0, 0);
                acc1 = __builtin_amdgcn_mfma_f32_32x32x16_f16(ah[ks + 1], bl[ks + 1], acc1, 0, 0, 0);
            }
            float nv  = nbuf[ct * 32 + ln31];
            int   col = ch * 128 + ct * 32 + ln31;
#pragma unroll
            for (int r = 0; r < 16; ++r) {
                float t  = (acc0[r] + acc1[r]) - nv;
                bool  gt = t > bv[r];
                bv[r] = gt ? t : bv[r];
                bi[r] = gt ? col : bi[r];
            }
        }
    }

    // Reduce across the 32 lanes (ln31) sharing each row; stride 33 words.
    __syncthreads();
    float* redv = (float*)sm;            // [128][33]
    int*   redi = (int*)(sm + 8448);     // [128][33]
#pragma unroll
    for (int r = 0; r < 16; ++r) {
        int row = (r & 3) + 8 * (r >> 2) + 4 * q + 32 * w;
        redv[row * 33 + ln31] = bv[r];
        redi[row * 33 + ln31] = bi[r];
    }
    __syncthreads();
    if (tid < 128) {
        float v  = redv[tid * 33];
        int   ix = redi[tid * 33];
#pragma unroll
        for (int j = 1; j < 32; ++j) {
            float vj = redv[tid * 33 + j];
            int   ij = redi[tid * 33 + j];
            if (vj > v) { v = vj; ix = ij; }
        }
        int r = r0 + tid;
        part_v[(size_t)r * 4 + slice] = v;
        part_i[(size_t)r * 4 + slice] = ix;
    }
}

// ---------------------------------------------------------------------------
// Kernel 3: fold the 4 slices in order (strict > keeps lowest-index winner,
// identical to a sequential scan of all 32 chunks).
// ---------------------------------------------------------------------------
__global__ __launch_bounds__(256) void k_merge(const float* __restrict__ part_v,
                                               const int* __restrict__ part_i,
                                               int* __restrict__ out) {
    int r = blockIdx.x * 256 + threadIdx.x;   // 65536 threads
    float4 pv = *reinterpret_cast<const float4*>(part_v + (size_t)r * 4);
    int4   pi = *reinterpret_cast<const int4*>(part_i + (size_t)r * 4);
    float v = pv.x; int ix = pi.x;
    if (pv.y > v) { v = pv.y; ix = pi.y; }
    if (pv.z > v) { v = pv.z; ix = pi.z; }
    if (pv.w > v) { v = pv.w; ix = pi.w; }
    out[r] = ix;
}

// ---------------------------------------------------------------------------
extern "C" void kernel_launch(void* const* d_in, const int* in_sizes, int n_in,
                              void* d_out, int out_size, void* d_ws, size_t ws_size,
                              hipStream_t stream) {
    (void)n_in; (void)out_size; (void)ws_size;
    const float* x  = (const float*)d_in[0];
    const float* W1 = (const float*)d_in[1];
    const float* b1 = (const float*)d_in[2];
    const float* gm = (const float*)d_in[3];
    const float* bt = (const float*)d_in[4];
    const float* mu = (const float*)d_in[5];
    const float* vr = (const float*)d_in[6];
    const float* W2 = (const float*)d_in[7];
    const float* b2 = (const float*)d_in[8];
    const float* W3 = (const float*)d_in[9];
    const float* b3 = (const float*)d_in[10];
    const float* cb = (const float*)d_in[11];

    // Workspace layout (~20.3 MB)
    char* ws = (char*)d_ws;
    float* norms = (float*)ws;                    // 16 KB
    f16* cbh = (f16*)(ws + 16384);                // 512 KB
    f16* cbl = (f16*)(ws + 540672);               // 512 KB
    f16* w1h = (f16*)(ws + 1064960);              // 128 KB
    f16* w1l = (f16*)(ws + 1196032);              // 128 KB
    f16* w2h = (f16*)(ws + 1327104);              // 64 KB
    f16* w2l = (f16*)(ws + 1392640);              // 64 KB
    f16* w3h = (f16*)(ws + 1458176);              // 16 KB
    f16* w3l = (f16*)(ws + 1474560);              // 16 KB
    f16* Zh  = (f16*)(ws + 1490944);              // 8 MB
    f16* Zl  = (f16*)(ws + 9879552);              // 8 MB
    float* part_v = (float*)(ws + 18268160);      // 1 MB
    int*   part_i = (int*)(ws + 19316736);        // 1 MB
    int* out = (int*)d_out;

    const int B = in_sizes[0] / IN_DIM;  // 65536

    k_norms<<<K_CODES / 256, 256, 0, stream>>>(cb, norms);
    k_prep<<<1440, 256, 0, stream>>>(W1, W2, W3, cb, w1h, w1l, w2h, w2l,
                                     w3h, w3l, cbh, cbl);
    k_encoder_mfma<<<B / 32, 256, 0, stream>>>(x, w1h, w1l, w2h, w2l, w3h, w3l,
                                               b1, gm, bt, mu, vr, b2, b3, Zh, Zl);
    dim3 ag(B / 128, 4);
    k_argmin_mfma<<<ag, 256, 0, stream>>>(Zh, Zl, cbh, cbl, norms, part_v, part_i);
    k_merge<<<B / 256, 256, 0, stream>>>(part_v, part_i, out);
}